// Round 8
// baseline (231.319 us; speedup 1.0000x reference)
//
#include <hip/hip_runtime.h>

#define NB 8
#define NL 512
#define ND 512
#define NH 8
#define NDK 64
#define NR 129
#define NTOK 4096
#define RPAD 132

typedef unsigned short u16;
typedef unsigned int u32;
typedef __attribute__((ext_vector_type(4))) float f32x4;
typedef __attribute__((ext_vector_type(8))) u16 u16x8;
typedef __attribute__((ext_vector_type(8))) __bf16 bf16x8;

__device__ __forceinline__ u16 f2bf(float f) {
  u32 u = __float_as_uint(f);
  u += 0x7FFFu + ((u >> 16) & 1u);
  return (u16)(u >> 16);
}
__device__ __forceinline__ float bf2f(u16 s) {
  return __uint_as_float(((u32)s) << 16);
}

// ---------------------------------------------------------------------------
// K0: fp32 -> bf16 conversion / packing.
//   xb    [4096][512]       = bf16(x)
//   Wqt/Wkt/Wot [512][512]  = bf16(W^T)   (row = out-dim n, col = in-dim k)
//   relkb [8][129][64]      = bf16(rel_k) head-major
// ---------------------------------------------------------------------------
__global__ __launch_bounds__(256) void convert_pack(
    const float* __restrict__ x, const float* __restrict__ Wq,
    const float* __restrict__ Wk, const float* __restrict__ Wo,
    const float* __restrict__ rel_k, u16* __restrict__ xb,
    u16* __restrict__ Wqt, u16* __restrict__ Wkt, u16* __restrict__ Wot,
    u16* __restrict__ relkb) {
  const int stride = gridDim.x * blockDim.x;
  const int g0 = blockIdx.x * blockDim.x + threadIdx.x;
  for (int i = g0; i < NTOK * ND; i += stride) xb[i] = f2bf(x[i]);
  for (int i = g0; i < ND * ND; i += stride) {
    int r = i >> 9, c = i & 511;
    Wqt[c * ND + r] = f2bf(Wq[i]);
    Wkt[c * ND + r] = f2bf(Wk[i]);
    Wot[c * ND + r] = f2bf(Wo[i]);
  }
  for (int i = g0; i < NR * NH * NDK; i += stride) {
    int j = i >> 9, rest = i & 511;
    int h = rest >> 6, d = rest & 63;
    relkb[(h * NR + j) * NDK + d] = f2bf(rel_k[i]);
  }
}

// ---------------------------------------------------------------------------
// K1/K5: C[4096][512] = A[4096][512] @ W (Wt given transposed) + bias
// MODE 0: write bf16 into head layout [b][h][l][d]  (Q / K projection)
// MODE 1: write fp32 flat [row][c]                  (final output)
// 128x128 tile, BK=32, 4 waves (2x2), each wave 64x64 via 4x4 mfma 16x16x32.
// ---------------------------------------------------------------------------
template <int MODE>
__global__ __launch_bounds__(256) void gemm_xw(const u16* __restrict__ A,
                                               const u16* __restrict__ Wt,
                                               const float* __restrict__ bias,
                                               void* __restrict__ outp) {
  constexpr int AST = 40;  // LDS row stride (bf16): 80 B, 16B-aligned, conflict-free
  __shared__ alignas(16) u16 As[128 * AST];
  __shared__ alignas(16) u16 Bs[128 * AST];
  const int tid = threadIdx.x;
  const int lane = tid & 63, wave = tid >> 6;
  const int wm = wave >> 1, wn = wave & 1;
  const int m0 = blockIdx.x * 128, n0 = blockIdx.y * 128;
  const int kq = (lane >> 4) << 3, rl = lane & 15;
  const f32x4 zero = {0.f, 0.f, 0.f, 0.f};
  f32x4 acc[4][4];
#pragma unroll
  for (int i = 0; i < 4; ++i)
#pragma unroll
    for (int j = 0; j < 4; ++j) acc[i][j] = zero;

  for (int k0 = 0; k0 < 512; k0 += 32) {
    __syncthreads();
#pragma unroll
    for (int r = 0; r < 2; ++r) {
      int idx = r * 256 + tid;          // 512 segments of 16 B
      int row = idx >> 2, seg = (idx & 3) << 3;
      *(u16x8*)&As[row * AST + seg] =
          *(const u16x8*)&A[(m0 + row) * 512 + k0 + seg];
      *(u16x8*)&Bs[row * AST + seg] =
          *(const u16x8*)&Wt[(n0 + row) * 512 + k0 + seg];
    }
    __syncthreads();
    bf16x8 af[4], bg[4];
#pragma unroll
    for (int f = 0; f < 4; ++f)
      af[f] = *(const bf16x8*)&As[(wm * 64 + f * 16 + rl) * AST + kq];
#pragma unroll
    for (int f = 0; f < 4; ++f)
      bg[f] = *(const bf16x8*)&Bs[(wn * 64 + f * 16 + rl) * AST + kq];
#pragma unroll
    for (int i = 0; i < 4; ++i)
#pragma unroll
      for (int j = 0; j < 4; ++j)
        acc[i][j] = __builtin_amdgcn_mfma_f32_16x16x32_bf16(af[i], bg[j],
                                                            acc[i][j], 0, 0, 0);
  }

  const int rb = (lane >> 4) << 2;
#pragma unroll
  for (int i = 0; i < 4; ++i) {
#pragma unroll
    for (int j = 0; j < 4; ++j) {
      const int c = n0 + wn * 64 + j * 16 + rl;
      const float bv = bias[c];
#pragma unroll
      for (int r = 0; r < 4; ++r) {
        const int row = m0 + wm * 64 + i * 16 + rb + r;
        const float v = acc[i][j][r] + bv;
        if (MODE == 0) {
          const int b = row >> 9, l = row & 511, h = c >> 6, d = c & 63;
          ((u16*)outp)[((size_t)(b * NH + h) * NL + l) * NDK + d] = f2bf(v);
        } else {
          ((float*)outp)[(size_t)row * ND + c] = v;
        }
      }
    }
  }
}

// ---------------------------------------------------------------------------
// K2: S[bh][512][512] = Q[bh] @ K[bh]^T   (fp32 out, unscaled)
// ---------------------------------------------------------------------------
__global__ __launch_bounds__(256) void gemm_qkt(const u16* __restrict__ Qb,
                                                const u16* __restrict__ Kb,
                                                float* __restrict__ S) {
  constexpr int AST = 40;
  __shared__ alignas(16) u16 As[128 * AST];
  __shared__ alignas(16) u16 Bs[128 * AST];
  const int tid = threadIdx.x;
  const int lane = tid & 63, wave = tid >> 6;
  const int wm = wave >> 1, wn = wave & 1;
  const int bh = blockIdx.z;
  const u16* Aq = Qb + (size_t)bh * NL * NDK;
  const u16* Bk = Kb + (size_t)bh * NL * NDK;
  float* Sout = S + (size_t)bh * NL * NL;
  const int m0 = blockIdx.x * 128, n0 = blockIdx.y * 128;
  const int kq = (lane >> 4) << 3, rl = lane & 15;
  const f32x4 zero = {0.f, 0.f, 0.f, 0.f};
  f32x4 acc[4][4];
#pragma unroll
  for (int i = 0; i < 4; ++i)
#pragma unroll
    for (int j = 0; j < 4; ++j) acc[i][j] = zero;

  for (int k0 = 0; k0 < 64; k0 += 32) {
    __syncthreads();
#pragma unroll
    for (int r = 0; r < 2; ++r) {
      int idx = r * 256 + tid;
      int row = idx >> 2, seg = (idx & 3) << 3;
      *(u16x8*)&As[row * AST + seg] =
          *(const u16x8*)&Aq[(m0 + row) * NDK + k0 + seg];
      *(u16x8*)&Bs[row * AST + seg] =
          *(const u16x8*)&Bk[(n0 + row) * NDK + k0 + seg];
    }
    __syncthreads();
    bf16x8 af[4], bg[4];
#pragma unroll
    for (int f = 0; f < 4; ++f)
      af[f] = *(const bf16x8*)&As[(wm * 64 + f * 16 + rl) * AST + kq];
#pragma unroll
    for (int f = 0; f < 4; ++f)
      bg[f] = *(const bf16x8*)&Bs[(wn * 64 + f * 16 + rl) * AST + kq];
#pragma unroll
    for (int i = 0; i < 4; ++i)
#pragma unroll
      for (int j = 0; j < 4; ++j)
        acc[i][j] = __builtin_amdgcn_mfma_f32_16x16x32_bf16(af[i], bg[j],
                                                            acc[i][j], 0, 0, 0);
  }

  const int rb = (lane >> 4) << 2;
#pragma unroll
  for (int i = 0; i < 4; ++i)
#pragma unroll
    for (int j = 0; j < 4; ++j) {
      const int c = n0 + wn * 64 + j * 16 + rl;
#pragma unroll
      for (int r = 0; r < 4; ++r) {
        const int row = m0 + wm * 64 + i * 16 + rb + r;
        Sout[(size_t)row * NL + c] = acc[i][j][r];
      }
    }
}

// ---------------------------------------------------------------------------
// K3: R[bh][l][j] = Q[bh,l] . rel_k[j,h]   (j = 0..128, fp32, stride RPAD)
// grid (L/128, B*H); block 256: thread = (row 0..127, half 0..1)
// ---------------------------------------------------------------------------
__global__ __launch_bounds__(256) void rel_scores_k(const u16* __restrict__ Qb,
                                                    const u16* __restrict__ relkb,
                                                    float* __restrict__ R) {
  __shared__ float relk_f[NR * NDK];  // 33 KB
  const int tid = threadIdx.x;
  const int bh = blockIdx.y, h = bh & 7, l0 = blockIdx.x * 128;
  for (int i = tid; i < NR * NDK; i += 256)
    relk_f[i] = bf2f(relkb[h * NR * NDK + i]);
  __syncthreads();
  const int row = tid >> 1, half = tid & 1;
  const u16* qrow = Qb + ((size_t)bh * NL + l0 + row) * NDK;
  float q[64];
#pragma unroll
  for (int v = 0; v < 8; ++v) {
    u16x8 t = *(const u16x8*)&qrow[v * 8];
#pragma unroll
    for (int e = 0; e < 8; ++e) q[v * 8 + e] = bf2f(t[e]);
  }
  float* Rrow = R + ((size_t)bh * NL + l0 + row) * RPAD;
  const int jend = half ? NR : 64;
#pragma unroll 1
  for (int j = half * 64; j < jend; ++j) {
    float acc = 0.f;
#pragma unroll
    for (int d = 0; d < 64; ++d) acc += q[d] * relk_f[j * 64 + d];
    Rrow[j] = acc;
  }
}

// ---------------------------------------------------------------------------
// K4: per row (b,h,l): softmax((S + R[relidx])/8) -> 129-bin weights -> GEMV
// with rel_v[h] -> OH bf16 [b][l][h*64+d].  One wave per row, 4 rows/block,
// all 4 rows of a block share the same (b,h) so rel_v[h] is staged in LDS.
// ---------------------------------------------------------------------------
__global__ __launch_bounds__(256) void softagg(const float* __restrict__ S,
                                               const float* __restrict__ R,
                                               const float* __restrict__ rel_v,
                                               u16* __restrict__ OH) {
  __shared__ float relv_s[NR * NDK];  // 33 KB
  __shared__ float w_s[4][RPAD];
  const int tid = threadIdx.x;
  const int lane = tid & 63, wave = tid >> 6;
  const int blk = blockIdx.x;     // 8192 blocks, 128 per (b,h)
  const int bh = blk >> 7;
  const int h = bh & 7, b = bh >> 3;
  const int l = ((blk & 127) << 2) + wave;
  const int gr = (bh << 9) + l;
  const float* Srow = S + (size_t)gr * NL;
  const float* Rrow = R + (size_t)gr * RPAD;

  // stage rel_v[:, h, :] -> LDS (f32), vectorized
  for (int i4 = tid; i4 < (NR * NDK) / 4; i4 += 256) {
    int j = i4 >> 4, dd = (i4 & 15) << 2;
    *(f32x4*)&relv_s[(j << 6) + dd] =
        *(const f32x4*)&rel_v[j * (NH * NDK) + h * NDK + dd];
  }
  for (int i = tid; i < 4 * RPAD; i += 256) ((float*)w_s)[i] = 0.f;
  __syncthreads();

  float* w = w_s[wave];
  const f32x4 s0 = *(const f32x4*)(Srow + lane * 8);
  const f32x4 s1 = *(const f32x4*)(Srow + lane * 8 + 4);
  float sv[8];
#pragma unroll
  for (int t = 0; t < 4; ++t) { sv[t] = s0[t]; sv[4 + t] = s1[t]; }

  float lg[8], mx = -1e30f;
#pragma unroll
  for (int t = 0; t < 8; ++t) {
    const int m = lane * 8 + t;
    const int dd = l - m;
    const int j = (dd <= -64) ? 0 : ((dd >= 64) ? 128 : dd + 64);
    lg[t] = (sv[t] + Rrow[j]) * 0.125f;
    mx = fmaxf(mx, lg[t]);
  }
#pragma unroll
  for (int off = 32; off >= 1; off >>= 1) mx = fmaxf(mx, __shfl_xor(mx, off, 64));
  float p[8], sum = 0.f;
#pragma unroll
  for (int t = 0; t < 8; ++t) { p[t] = __expf(lg[t] - mx); sum += p[t]; }
#pragma unroll
  for (int off = 32; off >= 1; off >>= 1) sum += __shfl_xor(sum, off, 64);
  const float inv = 1.f / sum;

  float t0 = 0.f, t1 = 0.f;
#pragma unroll
  for (int t = 0; t < 8; ++t) {
    const int m = lane * 8 + t;
    const int dd = l - m;
    const float a = p[t] * inv;
    if (dd >= 64) t1 += a;            // j = 128 bucket (m <= l-64)
    else if (dd <= -64) t0 += a;      // j = 0 bucket   (m >= l+64)
    else w[64 + dd] = a;              // unique central bin
  }
#pragma unroll
  for (int off = 32; off >= 1; off >>= 1) {
    t0 += __shfl_xor(t0, off, 64);
    t1 += __shfl_xor(t1, off, 64);
  }
  if (lane == 0) { w[0] = t0; w[128] = t1; }
  __syncthreads();  // make all bin writes (other lanes + lane0) visible

  // GEMV: out[d=lane] = sum_j w[j] * rel_v[j,h,d]
  float acc = 0.f;
#pragma unroll 4
  for (int j = 0; j < NR; ++j) acc += w[j] * relv_s[(j << 6) + lane];
  OH[((size_t)b * NL + l) * ND + h * NDK + lane] = f2bf(acc);
}

// ---------------------------------------------------------------------------
extern "C" void kernel_launch(void* const* d_in, const int* in_sizes, int n_in,
                              void* d_out, int out_size, void* d_ws,
                              size_t ws_size, hipStream_t stream) {
  const float* x = (const float*)d_in[0];
  const float* Wq = (const float*)d_in[1];
  const float* bq = (const float*)d_in[2];
  const float* Wk = (const float*)d_in[3];
  const float* bk = (const float*)d_in[4];
  // d_in[5], d_in[6] (Wv, bv) are dead: reference discards attn @ V.
  const float* Wo = (const float*)d_in[7];
  const float* bo = (const float*)d_in[8];
  const float* rel_k = (const float*)d_in[9];
  const float* rel_v = (const float*)d_in[10];

  char* ws = (char*)d_ws;
  size_t off = 0;
  auto alloc = [&](size_t bytes) {
    void* p = ws + off;
    off = (off + bytes + 255) & ~(size_t)255;
    return p;
  };
  u16* xb = (u16*)alloc((size_t)NTOK * ND * 2);
  u16* Wqt = (u16*)alloc((size_t)ND * ND * 2);
  u16* Wkt = (u16*)alloc((size_t)ND * ND * 2);
  u16* Wot = (u16*)alloc((size_t)ND * ND * 2);
  u16* relkb = (u16*)alloc((size_t)NH * NR * NDK * 2);
  u16* Qb = (u16*)alloc((size_t)NB * NH * NL * NDK * 2);
  u16* Kb = (u16*)alloc((size_t)NB * NH * NL * NDK * 2);
  float* Sbuf = (float*)alloc((size_t)NB * NH * NL * NL * 4);
  float* Rbuf = (float*)alloc((size_t)NB * NH * NL * RPAD * 4);
  u16* OH = (u16*)alloc((size_t)NTOK * ND * 2);

  convert_pack<<<2048, 256, 0, stream>>>(x, Wq, Wk, Wo, rel_k, xb, Wqt, Wkt,
                                         Wot, relkb);
  gemm_xw<0><<<dim3(32, 4), 256, 0, stream>>>(xb, Wqt, bq, Qb);
  gemm_xw<0><<<dim3(32, 4), 256, 0, stream>>>(xb, Wkt, bk, Kb);
  gemm_qkt<<<dim3(4, 4, 64), 256, 0, stream>>>(Qb, Kb, Sbuf);
  rel_scores_k<<<dim3(4, 64), 256, 0, stream>>>(Qb, relkb, Rbuf);
  softagg<<<8192, 256, 0, stream>>>(Sbuf, Rbuf, rel_v, OH);
  gemm_xw<1><<<dim3(32, 4), 256, 0, stream>>>(OH, Wot, bo, d_out);
}

// Round 14
// 194.572 us; speedup vs baseline: 1.1889x; 1.1889x over previous
//
#include <hip/hip_runtime.h>

#define NB 8
#define NL 512
#define ND 512
#define NH 8
#define NDK 64
#define NR 129
#define NTOK 4096
#define RPAD 132
#define PST 136  // P / relvT LDS row stride (bf16): 272 B, 2-way bank alias only

typedef unsigned short u16;
typedef unsigned int u32;
typedef __attribute__((ext_vector_type(4))) float f32x4;
typedef __attribute__((ext_vector_type(8))) u16 u16x8;
typedef __attribute__((ext_vector_type(8))) __bf16 bf16x8;

__device__ __forceinline__ u16 f2bf(float f) {
  u32 u = __float_as_uint(f);
  u += 0x7FFFu + ((u >> 16) & 1u);
  return (u16)(u >> 16);
}
__device__ __forceinline__ float bf2f(u16 s) {
  return __uint_as_float(((u32)s) << 16);
}

// ---------------------------------------------------------------------------
// K0: conversion / packing.
//  blocks [0,256):  xb[4096][512] = bf16(x)                  (coalesced)
//  blocks [256,260): bqk[1024] = {bq|bk};  relkb[8][129][64] = bf16(rel_k)
//  blocks [260,452): W transpose via LDS 64x64 tiles:
//     Wqkt[1024][512] = bf16([Wq|Wk]^T),  Wot[512][512] = bf16(Wo^T)
// ---------------------------------------------------------------------------
__global__ __launch_bounds__(256) void convert_pack(
    const float* __restrict__ x, const float* __restrict__ Wq,
    const float* __restrict__ Wk, const float* __restrict__ Wo,
    const float* __restrict__ bq, const float* __restrict__ bk,
    const float* __restrict__ rel_k, u16* __restrict__ xb,
    u16* __restrict__ Wqkt, u16* __restrict__ Wot, float* __restrict__ bqk,
    u16* __restrict__ relkb) {
  const int bx = blockIdx.x, tid = threadIdx.x;
  if (bx < 256) {  // x convert: 262144 u16x8 slots, 4 per thread
    const int tg = bx * 256 + tid;
#pragma unroll
    for (int it = 0; it < 4; ++it) {
      const int s = tg + it * 65536;
      f32x4 a = *(const f32x4*)&x[s * 8];
      f32x4 b = *(const f32x4*)&x[s * 8 + 4];
      u16x8 o;
#pragma unroll
      for (int e = 0; e < 4; ++e) { o[e] = f2bf(a[e]); o[4 + e] = f2bf(b[e]); }
      *(u16x8*)&xb[s * 8] = o;
    }
  } else if (bx < 260) {  // biases + rel_k pack
    const int t = (bx - 256) * 256 + tid;
    bqk[t] = (t < 512) ? bq[t] : bk[t - 512];
    for (int i = t; i < NR * NH * NDK; i += 1024) {
      int j = i >> 9, rest = i & 511;
      int h = rest >> 6, d = rest & 63;
      relkb[(h * NR + j) * NDK + d] = f2bf(rel_k[i]);
    }
  } else {  // W transpose tiles
    __shared__ u16 T[64 * 65];
    const int wi = bx - 260;
    const int mi = wi >> 6, ti = wi & 63;
    const int r0 = (ti >> 3) * 64, c0 = (ti & 7) * 64;
    const float* W = (mi == 0) ? Wq : (mi == 1) ? Wk : Wo;
#pragma unroll
    for (int it = 0; it < 4; ++it) {  // read coalesced, scatter to LDS
      const int s = tid + it * 256;
      const int row = s >> 4, c4 = s & 15;
      f32x4 v = *(const f32x4*)&W[(r0 + row) * ND + c0 + c4 * 4];
#pragma unroll
      for (int e = 0; e < 4; ++e) T[(c4 * 4 + e) * 65 + row] = f2bf(v[e]);
    }
    __syncthreads();
#pragma unroll
    for (int it = 0; it < 2; ++it) {  // gather from LDS, coalesced store
      const int s = tid + it * 256;
      const int oc = s >> 3, oseg = (s & 7) * 8;
      u16x8 o;
#pragma unroll
      for (int e = 0; e < 8; ++e) o[e] = T[oc * 65 + oseg + e];
      if (mi == 2)
        *(u16x8*)&Wot[(c0 + oc) * ND + r0 + oseg] = o;
      else
        *(u16x8*)&Wqkt[(mi * ND + c0 + oc) * ND + r0 + oseg] = o;
    }
  }
}

// ---------------------------------------------------------------------------
// K1/K4: C[4096][N] = A[4096][512] @ Wt^T + bias.  64x64 tile, BK=32, 4 waves
// (2x2), each wave 32x32 via 2x2 mfma 16x16x32.
// MODE 0: N=1024 (fused Q|K), bf16 out into head layout; Kb = outp + 2M elems
// MODE 1: N=512 (Wo), fp32 flat out
// ---------------------------------------------------------------------------
template <int MODE>
__global__ __launch_bounds__(256) void gemm_xw(const u16* __restrict__ A,
                                               const u16* __restrict__ Wt,
                                               const float* __restrict__ bias,
                                               void* __restrict__ outp) {
  constexpr int AST = 40;
  __shared__ alignas(16) u16 As[64 * AST];
  __shared__ alignas(16) u16 Bs[64 * AST];
  const int tid = threadIdx.x;
  const int lane = tid & 63, wave = tid >> 6;
  const int wm = wave >> 1, wn = wave & 1;
  const int m0 = blockIdx.x * 64, n0 = blockIdx.y * 64;
  const int kq = (lane >> 4) << 3, rl = lane & 15;
  const int srow = tid >> 2, sseg = (tid & 3) << 3;
  const f32x4 zero = {0.f, 0.f, 0.f, 0.f};
  f32x4 acc[2][2];
#pragma unroll
  for (int i = 0; i < 2; ++i)
#pragma unroll
    for (int j = 0; j < 2; ++j) acc[i][j] = zero;

  for (int k0 = 0; k0 < 512; k0 += 32) {
    __syncthreads();
    *(u16x8*)&As[srow * AST + sseg] =
        *(const u16x8*)&A[(m0 + srow) * 512 + k0 + sseg];
    *(u16x8*)&Bs[srow * AST + sseg] =
        *(const u16x8*)&Wt[(n0 + srow) * 512 + k0 + sseg];
    __syncthreads();
    bf16x8 af[2], bg[2];
#pragma unroll
    for (int f = 0; f < 2; ++f)
      af[f] = *(const bf16x8*)&As[(wm * 32 + f * 16 + rl) * AST + kq];
#pragma unroll
    for (int f = 0; f < 2; ++f)
      bg[f] = *(const bf16x8*)&Bs[(wn * 32 + f * 16 + rl) * AST + kq];
#pragma unroll
    for (int i = 0; i < 2; ++i)
#pragma unroll
      for (int j = 0; j < 2; ++j)
        acc[i][j] = __builtin_amdgcn_mfma_f32_16x16x32_bf16(af[i], bg[j],
                                                            acc[i][j], 0, 0, 0);
  }

  const int rb = (lane >> 4) << 2;
#pragma unroll
  for (int i = 0; i < 2; ++i) {
#pragma unroll
    for (int j = 0; j < 2; ++j) {
      const int c = n0 + wn * 32 + j * 16 + rl;
      const float bv = bias[c];
#pragma unroll
      for (int r = 0; r < 4; ++r) {
        const int row = m0 + wm * 32 + i * 16 + rb + r;
        const float v = acc[i][j][r] + bv;
        if (MODE == 0) {
          const int is_k = c >> 9, nn = c & 511;
          const int b = row >> 9, l = row & 511, h = nn >> 6, d = nn & 63;
          ((u16*)outp)[(size_t)is_k * (NB * NH * NL * NDK) +
                       ((size_t)(b * NH + h) * NL + l) * NDK + d] = f2bf(v);
        } else {
          ((float*)outp)[(size_t)row * ND + c] = v;
        }
      }
    }
  }
}

// ---------------------------------------------------------------------------
// K2: S[bh][512][512] = Q[bh] @ K[bh]^T   (fp32 out, unscaled) — unchanged
// ---------------------------------------------------------------------------
__global__ __launch_bounds__(256) void gemm_qkt(const u16* __restrict__ Qb,
                                                const u16* __restrict__ Kb,
                                                float* __restrict__ S) {
  constexpr int AST = 40;
  __shared__ alignas(16) u16 As[128 * AST];
  __shared__ alignas(16) u16 Bs[128 * AST];
  const int tid = threadIdx.x;
  const int lane = tid & 63, wave = tid >> 6;
  const int wm = wave >> 1, wn = wave & 1;
  const int bh = blockIdx.z;
  const u16* Aq = Qb + (size_t)bh * NL * NDK;
  const u16* Bk = Kb + (size_t)bh * NL * NDK;
  float* Sout = S + (size_t)bh * NL * NL;
  const int m0 = blockIdx.x * 128, n0 = blockIdx.y * 128;
  const int kq = (lane >> 4) << 3, rl = lane & 15;
  const f32x4 zero = {0.f, 0.f, 0.f, 0.f};
  f32x4 acc[4][4];
#pragma unroll
  for (int i = 0; i < 4; ++i)
#pragma unroll
    for (int j = 0; j < 4; ++j) acc[i][j] = zero;

  for (int k0 = 0; k0 < 64; k0 += 32) {
    __syncthreads();
#pragma unroll
    for (int r = 0; r < 2; ++r) {
      int idx = r * 256 + tid;
      int row = idx >> 2, seg = (idx & 3) << 3;
      *(u16x8*)&As[row * AST + seg] =
          *(const u16x8*)&Aq[(m0 + row) * NDK + k0 + seg];
      *(u16x8*)&Bs[row * AST + seg] =
          *(const u16x8*)&Bk[(n0 + row) * NDK + k0 + seg];
    }
    __syncthreads();
    bf16x8 af[4], bg[4];
#pragma unroll
    for (int f = 0; f < 4; ++f)
      af[f] = *(const bf16x8*)&As[(wm * 64 + f * 16 + rl) * AST + kq];
#pragma unroll
    for (int f = 0; f < 4; ++f)
      bg[f] = *(const bf16x8*)&Bs[(wn * 64 + f * 16 + rl) * AST + kq];
#pragma unroll
    for (int i = 0; i < 4; ++i)
#pragma unroll
      for (int j = 0; j < 4; ++j)
        acc[i][j] = __builtin_amdgcn_mfma_f32_16x16x32_bf16(af[i], bg[j],
                                                            acc[i][j], 0, 0, 0);
  }

  const int rb = (lane >> 4) << 2;
#pragma unroll
  for (int i = 0; i < 4; ++i)
#pragma unroll
    for (int j = 0; j < 4; ++j) {
      const int c = n0 + wn * 64 + j * 16 + rl;
#pragma unroll
      for (int r = 0; r < 4; ++r) {
        const int row = m0 + wm * 64 + i * 16 + rb + r;
        Sout[(size_t)row * NL + c] = acc[i][j][r];
      }
    }
}

// ---------------------------------------------------------------------------
// K3: R[bh][l][j] = Q[bh,l] . rel_k[j,h]
// grid (8, 64): 64 rows/block; thread = (row 0..63, j-quarter 0..3);
// 4 independent accumulators break the FMA dependence chain.
// ---------------------------------------------------------------------------
__global__ __launch_bounds__(256) void rel_scores_k(const u16* __restrict__ Qb,
                                                    const u16* __restrict__ relkb,
                                                    float* __restrict__ R) {
  __shared__ float relk_f[NR * NDK];  // 33 KB
  const int tid = threadIdx.x;
  const int bh = blockIdx.y, h = bh & 7, l0 = blockIdx.x * 64;
  for (int i = tid; i < NR * NDK; i += 256)
    relk_f[i] = bf2f(relkb[h * NR * NDK + i]);
  __syncthreads();
  const int row = tid >> 2, jq = tid & 3;
  const u16* qrow = Qb + ((size_t)bh * NL + l0 + row) * NDK;
  float q[64];
#pragma unroll
  for (int v = 0; v < 8; ++v) {
    u16x8 t = *(const u16x8*)&qrow[v * 8];
#pragma unroll
    for (int e = 0; e < 8; ++e) q[v * 8 + e] = bf2f(t[e]);
  }
  float* Rrow = R + ((size_t)bh * NL + l0 + row) * RPAD;
  const int j0 = jq * 33, j1 = (j0 + 33 < NR) ? j0 + 33 : NR;
#pragma unroll 1
  for (int j = j0; j < j1; ++j) {
    float a0 = 0.f, a1 = 0.f, a2 = 0.f, a3 = 0.f;
    const float* rk = &relk_f[j * 64];
#pragma unroll
    for (int e = 0; e < 16; ++e) {
      a0 += q[e] * rk[e];
      a1 += q[16 + e] * rk[16 + e];
      a2 += q[32 + e] * rk[32 + e];
      a3 += q[48 + e] * rk[48 + e];
    }
    Rrow[j] = (a0 + a1) + (a2 + a3);
  }
}

// ---------------------------------------------------------------------------
// K4: softagg v2.  Grid (8 chunks, 64 bh); 256 thr = 4 waves x 16 rows.
// Per block: stage rel_v[:,h,:]^T as bf16 [d][j] (B-operand); per wave:
// 16 rows of softmax -> bf16 bin-weights P[16][PST] (j=1..127 central bins;
// tails j=0/128 kept f32 in t0s/t1s); then 4 k-step MFMA (16x64 output)
// + f32 tail fixup in epilogue.  Replaces the 258-DS-op/row serial GEMV.
// ---------------------------------------------------------------------------
__global__ __launch_bounds__(256) void softagg(const float* __restrict__ S,
                                               const float* __restrict__ R,
                                               const float* __restrict__ rel_v,
                                               u16* __restrict__ OH) {
  __shared__ alignas(16) u16 relvT[64 * PST];      // [d][j] bf16
  __shared__ alignas(16) u16 P_s[4][16 * PST];     // per-wave bin weights
  __shared__ float t0s[4][16], t1s[4][16];         // f32 tail weights
  const int tid = threadIdx.x;
  const int lane = tid & 63, wave = tid >> 6;
  const int chunk = blockIdx.x, bh = blockIdx.y;
  const int h = bh & 7, b = bh >> 3;

  // stage relvT: j in [0,128) from rel_v (coalesced 64-lane reads), rest 0
#pragma unroll 4
  for (int jb = 0; jb < 128; jb += 4) {
    const int j = jb + (tid >> 6), d = tid & 63;
    relvT[d * PST + j] = f2bf(rel_v[j * (NH * NDK) + h * NDK + d]);
  }
  if ((tid & 3) == 0) {  // zero cols 128..135
    const u16x8 z = {0, 0, 0, 0, 0, 0, 0, 0};
    *(u16x8*)&relvT[(tid >> 2) * PST + 128] = z;
  }
  {  // zero all of P (4*16*136 bf16 = 1088 u16x8 slots)
    const u16x8 z = {0, 0, 0, 0, 0, 0, 0, 0};
    for (int i = tid; i < 1088; i += 256) *(u16x8*)&((u16*)P_s)[i * 8] = z;
  }
  __syncthreads();

  u16* P_w = P_s[wave];
#pragma unroll 2
  for (int r = 0; r < 16; ++r) {
    const int l = chunk * 64 + wave * 16 + r;
    const float* Srow = S + ((size_t)bh * NL + l) * NL;
    const float* Rrow = R + ((size_t)bh * NL + l) * RPAD;
    const f32x4 s0 = *(const f32x4*)(Srow + lane * 8);
    const f32x4 s1 = *(const f32x4*)(Srow + lane * 8 + 4);
    float sv[8];
#pragma unroll
    for (int t = 0; t < 4; ++t) { sv[t] = s0[t]; sv[4 + t] = s1[t]; }

    float lg[8], mx = -1e30f;
#pragma unroll
    for (int t = 0; t < 8; ++t) {
      const int m = lane * 8 + t;
      const int dd = l - m;
      const int j = (dd <= -64) ? 0 : ((dd >= 64) ? 128 : dd + 64);
      lg[t] = (sv[t] + Rrow[j]) * 0.125f;
      mx = fmaxf(mx, lg[t]);
    }
#pragma unroll
    for (int off = 32; off >= 1; off >>= 1) mx = fmaxf(mx, __shfl_xor(mx, off, 64));
    float p[8], sum = 0.f;
#pragma unroll
    for (int t = 0; t < 8; ++t) { p[t] = __expf(lg[t] - mx); sum += p[t]; }
#pragma unroll
    for (int off = 32; off >= 1; off >>= 1) sum += __shfl_xor(sum, off, 64);
    const float inv = 1.f / sum;

    float t0 = 0.f, t1 = 0.f;
#pragma unroll
    for (int t = 0; t < 8; ++t) {
      const int m = lane * 8 + t;
      const int dd = l - m;
      const float a = p[t] * inv;
      if (dd >= 64) t1 += a;                        // j=128 tail (f32)
      else if (dd <= -64) t0 += a;                  // j=0 tail (f32)
      else P_w[r * PST + 64 + dd] = f2bf(a);        // central bin 1..127
    }
#pragma unroll
    for (int off = 32; off >= 1; off >>= 1) {
      t0 += __shfl_xor(t0, off, 64);
      t1 += __shfl_xor(t1, off, 64);
    }
    if (lane == 0) { t0s[wave][r] = t0; t1s[wave][r] = t1; }
  }

  // MFMA: D[16 rows][64 d] = P_w[16][128] @ relvT^T  (4 k-steps of 32)
  const int rl = lane & 15, kq = (lane >> 4) << 3;
  const f32x4 zero = {0.f, 0.f, 0.f, 0.f};
  f32x4 acc[4] = {zero, zero, zero, zero};
#pragma unroll
  for (int ks = 0; ks < 4; ++ks) {
    bf16x8 af = *(const bf16x8*)&P_w[rl * PST + ks * 32 + kq];
#pragma unroll
    for (int nt = 0; nt < 4; ++nt) {
      bf16x8 bg = *(const bf16x8*)&relvT[(nt * 16 + rl) * PST + ks * 32 + kq];
      acc[nt] = __builtin_amdgcn_mfma_f32_16x16x32_bf16(af, bg, acc[nt], 0, 0, 0);
    }
  }

  // epilogue: add f32 tail contributions, store bf16 head-layout
#pragma unroll
  for (int nt = 0; nt < 4; ++nt) {
    const int d = nt * 16 + rl;
    const float rv0 = rel_v[0 * (NH * NDK) + h * NDK + d];
    const float rv128 = rel_v[128 * (NH * NDK) + h * NDK + d];
#pragma unroll
    for (int reg = 0; reg < 4; ++reg) {
      const int rloc = (lane >> 4) * 4 + reg;
      const int l_out = chunk * 64 + wave * 16 + rloc;
      const float v = acc[nt][reg] + t0s[wave][rloc] * rv0 + t1s[wave][rloc] * rv128;
      OH[((size_t)b * NL + l_out) * ND + h * NDK + d] = f2bf(v);
    }
  }
}

// ---------------------------------------------------------------------------
extern "C" void kernel_launch(void* const* d_in, const int* in_sizes, int n_in,
                              void* d_out, int out_size, void* d_ws,
                              size_t ws_size, hipStream_t stream) {
  const float* x = (const float*)d_in[0];
  const float* Wq = (const float*)d_in[1];
  const float* bq = (const float*)d_in[2];
  const float* Wk = (const float*)d_in[3];
  const float* bk = (const float*)d_in[4];
  // d_in[5], d_in[6] (Wv, bv) are dead: reference discards attn @ V.
  const float* Wo = (const float*)d_in[7];
  const float* bo = (const float*)d_in[8];
  const float* rel_k = (const float*)d_in[9];
  const float* rel_v = (const float*)d_in[10];

  char* ws = (char*)d_ws;
  size_t off = 0;
  auto alloc = [&](size_t bytes) {
    void* p = ws + off;
    off = (off + bytes + 255) & ~(size_t)255;
    return p;
  };
  u16* xb = (u16*)alloc((size_t)NTOK * ND * 2);
  u16* Wqkt = (u16*)alloc((size_t)2 * ND * ND * 2);
  u16* Wot = (u16*)alloc((size_t)ND * ND * 2);
  float* bqk = (float*)alloc((size_t)2 * ND * 4);
  u16* relkb = (u16*)alloc((size_t)NH * NR * NDK * 2);
  u16* QKb = (u16*)alloc((size_t)2 * NB * NH * NL * NDK * 2);  // Qb | Kb
  float* Sbuf = (float*)alloc((size_t)NB * NH * NL * NL * 4);
  float* Rbuf = (float*)alloc((size_t)NB * NH * NL * RPAD * 4);
  u16* OH = (u16*)alloc((size_t)NTOK * ND * 2);
  u16* Qb = QKb;
  u16* Kb = QKb + (size_t)NB * NH * NL * NDK;

  convert_pack<<<452, 256, 0, stream>>>(x, Wq, Wk, Wo, bq, bk, rel_k, xb, Wqkt,
                                        Wot, bqk, relkb);
  gemm_xw<0><<<dim3(64, 16), 256, 0, stream>>>(xb, Wqkt, bqk, QKb);
  gemm_qkt<<<dim3(4, 4, 64), 256, 0, stream>>>(Qb, Kb, Sbuf);
  rel_scores_k<<<dim3(8, 64), 256, 0, stream>>>(Qb, relkb, Rbuf);
  softagg<<<dim3(8, 64), 256, 0, stream>>>(Sbuf, Rbuf, rel_v, OH);
  gemm_xw<1><<<dim3(64, 8), 256, 0, stream>>>(OH, Wot, bo, d_out);
}

// Round 16
// 160.622 us; speedup vs baseline: 1.4402x; 1.2114x over previous
//
#include <hip/hip_runtime.h>

#define NB 8
#define NL 512
#define ND 512
#define NH 8
#define NDK 64
#define NR 129
#define NRP 144  // padded rel rows (MFMA N-dim: 9x16)
#define NTOK 4096
#define PST 136  // P / relvT LDS row stride (bf16): 272 B, 2-way bank alias only

typedef unsigned short u16;
typedef unsigned int u32;
typedef __attribute__((ext_vector_type(4))) float f32x4;
typedef __attribute__((ext_vector_type(8))) u16 u16x8;
typedef __attribute__((ext_vector_type(8))) __bf16 bf16x8;

__device__ __forceinline__ u16 f2bf(float f) {
  u32 u = __float_as_uint(f);
  u += 0x7FFFu + ((u >> 16) & 1u);
  return (u16)(u >> 16);
}
__device__ __forceinline__ float bf2f(u16 s) {
  return __uint_as_float(((u32)s) << 16);
}

// ---------------------------------------------------------------------------
// K0: conversion / packing.
//  blocks [0,256):  xb[4096][512] = bf16(x)                  (coalesced)
//  blocks [256,260): bqk[1024] = {bq|bk};  relkb[8][144][64] = bf16(rel_k)
//  blocks [260,452): W transpose via LDS 64x64 tiles:
//     Wqkt[1024][512] = bf16([Wq|Wk]^T),  Wot[512][512] = bf16(Wo^T)
// ---------------------------------------------------------------------------
__global__ __launch_bounds__(256) void convert_pack(
    const float* __restrict__ x, const float* __restrict__ Wq,
    const float* __restrict__ Wk, const float* __restrict__ Wo,
    const float* __restrict__ bq, const float* __restrict__ bk,
    const float* __restrict__ rel_k, u16* __restrict__ xb,
    u16* __restrict__ Wqkt, u16* __restrict__ Wot, float* __restrict__ bqk,
    u16* __restrict__ relkb) {
  const int bx = blockIdx.x, tid = threadIdx.x;
  if (bx < 256) {  // x convert: 262144 u16x8 slots, 4 per thread
    const int tg = bx * 256 + tid;
#pragma unroll
    for (int it = 0; it < 4; ++it) {
      const int s = tg + it * 65536;
      f32x4 a = *(const f32x4*)&x[s * 8];
      f32x4 b = *(const f32x4*)&x[s * 8 + 4];
      u16x8 o;
#pragma unroll
      for (int e = 0; e < 4; ++e) { o[e] = f2bf(a[e]); o[4 + e] = f2bf(b[e]); }
      *(u16x8*)&xb[s * 8] = o;
    }
  } else if (bx < 260) {  // biases + rel_k pack (j-major into 144-padded rows)
    const int t = (bx - 256) * 256 + tid;
    bqk[t] = (t < 512) ? bq[t] : bk[t - 512];
    for (int i = t; i < NR * NH * NDK; i += 1024) {
      int j = i >> 9, rest = i & 511;
      int h = rest >> 6, d = rest & 63;
      relkb[((size_t)h * NRP + j) * NDK + d] = f2bf(rel_k[i]);
    }
  } else {  // W transpose tiles
    __shared__ u16 T[64 * 65];
    const int wi = bx - 260;
    const int mi = wi >> 6, ti = wi & 63;
    const int r0 = (ti >> 3) * 64, c0 = (ti & 7) * 64;
    const float* W = (mi == 0) ? Wq : (mi == 1) ? Wk : Wo;
#pragma unroll
    for (int it = 0; it < 4; ++it) {  // read coalesced, scatter to LDS
      const int s = tid + it * 256;
      const int row = s >> 4, c4 = s & 15;
      f32x4 v = *(const f32x4*)&W[(r0 + row) * ND + c0 + c4 * 4];
#pragma unroll
      for (int e = 0; e < 4; ++e) T[(c4 * 4 + e) * 65 + row] = f2bf(v[e]);
    }
    __syncthreads();
#pragma unroll
    for (int it = 0; it < 2; ++it) {  // gather from LDS, coalesced store
      const int s = tid + it * 256;
      const int oc = s >> 3, oseg = (s & 7) * 8;
      u16x8 o;
#pragma unroll
      for (int e = 0; e < 8; ++e) o[e] = T[oc * 65 + oseg + e];
      if (mi == 2)
        *(u16x8*)&Wot[(c0 + oc) * ND + r0 + oseg] = o;
      else
        *(u16x8*)&Wqkt[(mi * ND + c0 + oc) * ND + r0 + oseg] = o;
    }
  }
}

// ---------------------------------------------------------------------------
// K1/K5: C[4096][N] = A[4096][512] @ Wt^T + bias.  64x64 tile, BK=32, 4 waves
// (2x2), each wave 32x32 via 2x2 mfma 16x16x32.
// MODE 0: N=1024 (fused Q|K), bf16 out into head layout; Kb = outp + 2M elems
// MODE 1: N=512 (Wo), fp32 flat out
// ---------------------------------------------------------------------------
template <int MODE>
__global__ __launch_bounds__(256) void gemm_xw(const u16* __restrict__ A,
                                               const u16* __restrict__ Wt,
                                               const float* __restrict__ bias,
                                               void* __restrict__ outp) {
  constexpr int AST = 40;
  __shared__ alignas(16) u16 As[64 * AST];
  __shared__ alignas(16) u16 Bs[64 * AST];
  const int tid = threadIdx.x;
  const int lane = tid & 63, wave = tid >> 6;
  const int wm = wave >> 1, wn = wave & 1;
  const int m0 = blockIdx.x * 64, n0 = blockIdx.y * 64;
  const int kq = (lane >> 4) << 3, rl = lane & 15;
  const int srow = tid >> 2, sseg = (tid & 3) << 3;
  const f32x4 zero = {0.f, 0.f, 0.f, 0.f};
  f32x4 acc[2][2];
#pragma unroll
  for (int i = 0; i < 2; ++i)
#pragma unroll
    for (int j = 0; j < 2; ++j) acc[i][j] = zero;

  for (int k0 = 0; k0 < 512; k0 += 32) {
    __syncthreads();
    *(u16x8*)&As[srow * AST + sseg] =
        *(const u16x8*)&A[(m0 + srow) * 512 + k0 + sseg];
    *(u16x8*)&Bs[srow * AST + sseg] =
        *(const u16x8*)&Wt[(n0 + srow) * 512 + k0 + sseg];
    __syncthreads();
    bf16x8 af[2], bg[2];
#pragma unroll
    for (int f = 0; f < 2; ++f)
      af[f] = *(const bf16x8*)&As[(wm * 32 + f * 16 + rl) * AST + kq];
#pragma unroll
    for (int f = 0; f < 2; ++f)
      bg[f] = *(const bf16x8*)&Bs[(wn * 32 + f * 16 + rl) * AST + kq];
#pragma unroll
    for (int i = 0; i < 2; ++i)
#pragma unroll
      for (int j = 0; j < 2; ++j)
        acc[i][j] = __builtin_amdgcn_mfma_f32_16x16x32_bf16(af[i], bg[j],
                                                            acc[i][j], 0, 0, 0);
  }

  const int rb = (lane >> 4) << 2;
#pragma unroll
  for (int i = 0; i < 2; ++i) {
#pragma unroll
    for (int j = 0; j < 2; ++j) {
      const int c = n0 + wn * 32 + j * 16 + rl;
      const float bv = bias[c];
#pragma unroll
      for (int r = 0; r < 4; ++r) {
        const int row = m0 + wm * 32 + i * 16 + rb + r;
        const float v = acc[i][j][r] + bv;
        if (MODE == 0) {
          const int is_k = c >> 9, nn = c & 511;
          const int b = row >> 9, l = row & 511, h = nn >> 6, d = nn & 63;
          ((u16*)outp)[(size_t)is_k * (NB * NH * NL * NDK) +
                       ((size_t)(b * NH + h) * NL + l) * NDK + d] = f2bf(v);
        } else {
          ((float*)outp)[(size_t)row * ND + c] = v;
        }
      }
    }
  }
}

// ---------------------------------------------------------------------------
// K2: S[bh][512][512] = bf16(Q[bh] @ K[bh]^T)   (bf16 out, unscaled)
// ---------------------------------------------------------------------------
__global__ __launch_bounds__(256) void gemm_qkt(const u16* __restrict__ Qb,
                                                const u16* __restrict__ Kb,
                                                u16* __restrict__ S) {
  constexpr int AST = 40;
  __shared__ alignas(16) u16 As[128 * AST];
  __shared__ alignas(16) u16 Bs[128 * AST];
  const int tid = threadIdx.x;
  const int lane = tid & 63, wave = tid >> 6;
  const int wm = wave >> 1, wn = wave & 1;
  const int bh = blockIdx.z;
  const u16* Aq = Qb + (size_t)bh * NL * NDK;
  const u16* Bk = Kb + (size_t)bh * NL * NDK;
  u16* Sout = S + (size_t)bh * NL * NL;
  const int m0 = blockIdx.x * 128, n0 = blockIdx.y * 128;
  const int kq = (lane >> 4) << 3, rl = lane & 15;
  const f32x4 zero = {0.f, 0.f, 0.f, 0.f};
  f32x4 acc[4][4];
#pragma unroll
  for (int i = 0; i < 4; ++i)
#pragma unroll
    for (int j = 0; j < 4; ++j) acc[i][j] = zero;

  for (int k0 = 0; k0 < 64; k0 += 32) {
    __syncthreads();
#pragma unroll
    for (int r = 0; r < 2; ++r) {
      int idx = r * 256 + tid;
      int row = idx >> 2, seg = (idx & 3) << 3;
      *(u16x8*)&As[row * AST + seg] =
          *(const u16x8*)&Aq[(m0 + row) * NDK + k0 + seg];
      *(u16x8*)&Bs[row * AST + seg] =
          *(const u16x8*)&Bk[(n0 + row) * NDK + k0 + seg];
    }
    __syncthreads();
    bf16x8 af[4], bg[4];
#pragma unroll
    for (int f = 0; f < 4; ++f)
      af[f] = *(const bf16x8*)&As[(wm * 64 + f * 16 + rl) * AST + kq];
#pragma unroll
    for (int f = 0; f < 4; ++f)
      bg[f] = *(const bf16x8*)&Bs[(wn * 64 + f * 16 + rl) * AST + kq];
#pragma unroll
    for (int i = 0; i < 4; ++i)
#pragma unroll
      for (int j = 0; j < 4; ++j)
        acc[i][j] = __builtin_amdgcn_mfma_f32_16x16x32_bf16(af[i], bg[j],
                                                            acc[i][j], 0, 0, 0);
  }

  const int rb = (lane >> 4) << 2;
#pragma unroll
  for (int i = 0; i < 4; ++i)
#pragma unroll
    for (int j = 0; j < 4; ++j) {
      const int c = n0 + wn * 64 + j * 16 + rl;
#pragma unroll
      for (int r = 0; r < 4; ++r) {
        const int row = m0 + wm * 64 + i * 16 + rb + r;
        Sout[(size_t)row * NL + c] = f2bf(acc[i][j][r]);
      }
    }
}

// ---------------------------------------------------------------------------
// K3: R[bh][l][0..143] = Q[bh] @ relkb[h]^T via MFMA (cols 129..143 junk,
// never read).  Grid (4 m-tiles, 64 bh); 4 waves, each 32 rows x 144 cols.
// Replaces the VALU rel_scores_k (41.7us, 12.6M bank-conflict cycles).
// ---------------------------------------------------------------------------
__global__ __launch_bounds__(256) void rel_scores_mfma(
    const u16* __restrict__ Qb, const u16* __restrict__ relkb,
    float* __restrict__ R) {
  constexpr int AST = 72;  // 144 B row stride: 2-way bank alias only
  __shared__ alignas(16) u16 Qs[128 * AST];  // 18 KB
  __shared__ alignas(16) u16 Bs[NRP * AST];  // 20.25 KB
  const int tid = threadIdx.x;
  const int lane = tid & 63, wave = tid >> 6;
  const int bh = blockIdx.y, h = bh & 7;
  const int m0 = blockIdx.x * 128;

  for (int i = tid; i < 128 * 8; i += 256) {  // Q tile 128x64
    int row = i >> 3, seg = (i & 7) << 3;
    *(u16x8*)&Qs[row * AST + seg] =
        *(const u16x8*)&Qb[((size_t)bh * NL + m0 + row) * NDK + seg];
  }
  for (int i = tid; i < NRP * 8; i += 256) {  // relk 144x64
    int row = i >> 3, seg = (i & 7) << 3;
    *(u16x8*)&Bs[row * AST + seg] =
        *(const u16x8*)&relkb[((size_t)h * NRP + row) * NDK + seg];
  }
  __syncthreads();

  const int rl = lane & 15, kq = (lane >> 4) << 3;
  const f32x4 zero = {0.f, 0.f, 0.f, 0.f};
  f32x4 acc[2][9];
#pragma unroll
  for (int i = 0; i < 2; ++i)
#pragma unroll
    for (int j = 0; j < 9; ++j) acc[i][j] = zero;

#pragma unroll
  for (int ks = 0; ks < 2; ++ks) {
    bf16x8 af[2], bg[9];
#pragma unroll
    for (int i = 0; i < 2; ++i)
      af[i] = *(const bf16x8*)&Qs[(wave * 32 + i * 16 + rl) * AST + ks * 32 + kq];
#pragma unroll
    for (int j = 0; j < 9; ++j)
      bg[j] = *(const bf16x8*)&Bs[(j * 16 + rl) * AST + ks * 32 + kq];
#pragma unroll
    for (int i = 0; i < 2; ++i)
#pragma unroll
      for (int j = 0; j < 9; ++j)
        acc[i][j] = __builtin_amdgcn_mfma_f32_16x16x32_bf16(af[i], bg[j],
                                                            acc[i][j], 0, 0, 0);
  }

  const int rb = (lane >> 4) << 2;
#pragma unroll
  for (int i = 0; i < 2; ++i)
#pragma unroll
    for (int j = 0; j < 9; ++j) {
      const int c = j * 16 + rl;
#pragma unroll
      for (int r = 0; r < 4; ++r) {
        const int row = m0 + wave * 32 + i * 16 + rb + r;
        R[((size_t)bh * NL + row) * NRP + c] = acc[i][j][r];
      }
    }
}

// ---------------------------------------------------------------------------
// K4: softagg.  Grid (8 chunks, 64 bh); 256 thr = 4 waves x 16 rows.
// Per block: stage rel_v[:,h,:]^T as bf16 [d][j] (B-operand); per wave:
// 16 rows of softmax -> bf16 bin-weights P[16][PST] (j=1..127 central bins;
// tails j=0/128 kept f32 in t0s/t1s); then 4 k-step MFMA (16x64 output)
// + f32 tail fixup in epilogue.  S is bf16 now.
// ---------------------------------------------------------------------------
__global__ __launch_bounds__(256) void softagg(const u16* __restrict__ S,
                                               const float* __restrict__ R,
                                               const float* __restrict__ rel_v,
                                               u16* __restrict__ OH) {
  __shared__ alignas(16) u16 relvT[64 * PST];      // [d][j] bf16
  __shared__ alignas(16) u16 P_s[4][16 * PST];     // per-wave bin weights
  __shared__ float t0s[4][16], t1s[4][16];         // f32 tail weights
  const int tid = threadIdx.x;
  const int lane = tid & 63, wave = tid >> 6;
  const int chunk = blockIdx.x, bh = blockIdx.y;
  const int h = bh & 7, b = bh >> 3;

  // stage relvT: j in [0,128) from rel_v (coalesced 64-lane reads), rest 0
#pragma unroll 4
  for (int jb = 0; jb < 128; jb += 4) {
    const int j = jb + (tid >> 6), d = tid & 63;
    relvT[d * PST + j] = f2bf(rel_v[j * (NH * NDK) + h * NDK + d]);
  }
  if ((tid & 3) == 0) {  // zero cols 128..135
    const u16x8 z = {0, 0, 0, 0, 0, 0, 0, 0};
    *(u16x8*)&relvT[(tid >> 2) * PST + 128] = z;
  }
  {  // zero all of P (4*16*136 bf16 = 1088 u16x8 slots)
    const u16x8 z = {0, 0, 0, 0, 0, 0, 0, 0};
    for (int i = tid; i < 1088; i += 256) *(u16x8*)&((u16*)P_s)[i * 8] = z;
  }
  __syncthreads();

  u16* P_w = P_s[wave];
#pragma unroll 2
  for (int r = 0; r < 16; ++r) {
    const int l = chunk * 64 + wave * 16 + r;
    const u16* Srow = S + ((size_t)bh * NL + l) * NL;
    const float* Rrow = R + ((size_t)bh * NL + l) * NRP;
    const u16x8 sraw = *(const u16x8*)(Srow + lane * 8);
    float sv[8];
#pragma unroll
    for (int t = 0; t < 8; ++t) sv[t] = bf2f(sraw[t]);

    float lg[8], mx = -1e30f;
#pragma unroll
    for (int t = 0; t < 8; ++t) {
      const int m = lane * 8 + t;
      const int dd = l - m;
      const int j = (dd <= -64) ? 0 : ((dd >= 64) ? 128 : dd + 64);
      lg[t] = (sv[t] + Rrow[j]) * 0.125f;
      mx = fmaxf(mx, lg[t]);
    }
#pragma unroll
    for (int off = 32; off >= 1; off >>= 1) mx = fmaxf(mx, __shfl_xor(mx, off, 64));
    float p[8], sum = 0.f;
#pragma unroll
    for (int t = 0; t < 8; ++t) { p[t] = __expf(lg[t] - mx); sum += p[t]; }
#pragma unroll
    for (int off = 32; off >= 1; off >>= 1) sum += __shfl_xor(sum, off, 64);
    const float inv = 1.f / sum;

    float t0 = 0.f, t1 = 0.f;
#pragma unroll
    for (int t = 0; t < 8; ++t) {
      const int m = lane * 8 + t;
      const int dd = l - m;
      const float a = p[t] * inv;
      if (dd >= 64) t1 += a;                        // j=128 tail (f32)
      else if (dd <= -64) t0 += a;                  // j=0 tail (f32)
      else P_w[r * PST + 64 + dd] = f2bf(a);        // central bin 1..127
    }
#pragma unroll
    for (int off = 32; off >= 1; off >>= 1) {
      t0 += __shfl_xor(t0, off, 64);
      t1 += __shfl_xor(t1, off, 64);
    }
    if (lane == 0) { t0s[wave][r] = t0; t1s[wave][r] = t1; }
  }

  // MFMA: D[16 rows][64 d] = P_w[16][128] @ relvT^T  (4 k-steps of 32)
  const int rl = lane & 15, kq = (lane >> 4) << 3;
  const f32x4 zero = {0.f, 0.f, 0.f, 0.f};
  f32x4 acc[4] = {zero, zero, zero, zero};
#pragma unroll
  for (int ks = 0; ks < 4; ++ks) {
    bf16x8 af = *(const bf16x8*)&P_w[rl * PST + ks * 32 + kq];
#pragma unroll
    for (int nt = 0; nt < 4; ++nt) {
      bf16x8 bg = *(const bf16x8*)&relvT[(nt * 16 + rl) * PST + ks * 32 + kq];
      acc[nt] = __builtin_amdgcn_mfma_f32_16x16x32_bf16(af, bg, acc[nt], 0, 0, 0);
    }
  }

  // epilogue: add f32 tail contributions, store bf16 head-layout
#pragma unroll
  for (int nt = 0; nt < 4; ++nt) {
    const int d = nt * 16 + rl;
    const float rv0 = rel_v[0 * (NH * NDK) + h * NDK + d];
    const float rv128 = rel_v[128 * (NH * NDK) + h * NDK + d];
#pragma unroll
    for (int reg = 0; reg < 4; ++reg) {
      const int rloc = (lane >> 4) * 4 + reg;
      const int l_out = chunk * 64 + wave * 16 + rloc;
      const float v = acc[nt][reg] + t0s[wave][rloc] * rv0 + t1s[wave][rloc] * rv128;
      OH[((size_t)b * NL + l_out) * ND + h * NDK + d] = f2bf(v);
    }
  }
}

// ---------------------------------------------------------------------------
extern "C" void kernel_launch(void* const* d_in, const int* in_sizes, int n_in,
                              void* d_out, int out_size, void* d_ws,
                              size_t ws_size, hipStream_t stream) {
  const float* x = (const float*)d_in[0];
  const float* Wq = (const float*)d_in[1];
  const float* bq = (const float*)d_in[2];
  const float* Wk = (const float*)d_in[3];
  const float* bk = (const float*)d_in[4];
  // d_in[5], d_in[6] (Wv, bv) are dead: reference discards attn @ V.
  const float* Wo = (const float*)d_in[7];
  const float* bo = (const float*)d_in[8];
  const float* rel_k = (const float*)d_in[9];
  const float* rel_v = (const float*)d_in[10];

  char* ws = (char*)d_ws;
  size_t off = 0;
  auto alloc = [&](size_t bytes) {
    void* p = ws + off;
    off = (off + bytes + 255) & ~(size_t)255;
    return p;
  };
  u16* xb = (u16*)alloc((size_t)NTOK * ND * 2);
  u16* Wqkt = (u16*)alloc((size_t)2 * ND * ND * 2);
  u16* Wot = (u16*)alloc((size_t)ND * ND * 2);
  float* bqk = (float*)alloc((size_t)2 * ND * 4);
  u16* relkb = (u16*)alloc((size_t)NH * NRP * NDK * 2);
  u16* QKb = (u16*)alloc((size_t)2 * NB * NH * NL * NDK * 2);  // Qb | Kb
  u16* Sbuf = (u16*)alloc((size_t)NB * NH * NL * NL * 2);      // bf16 S
  float* Rbuf = (float*)alloc((size_t)NB * NH * NL * NRP * 4);
  u16* OH = (u16*)alloc((size_t)NTOK * ND * 2);
  u16* Qb = QKb;
  u16* Kb = QKb + (size_t)NB * NH * NL * NDK;

  convert_pack<<<452, 256, 0, stream>>>(x, Wq, Wk, Wo, bq, bk, rel_k, xb, Wqkt,
                                        Wot, bqk, relkb);
  gemm_xw<0><<<dim3(64, 16), 256, 0, stream>>>(xb, Wqkt, bqk, QKb);
  gemm_qkt<<<dim3(4, 4, 64), 256, 0, stream>>>(Qb, Kb, Sbuf);
  rel_scores_mfma<<<dim3(4, 64), 256, 0, stream>>>(Qb, relkb, Rbuf);
  softagg<<<dim3(8, 64), 256, 0, stream>>>(Sbuf, Rbuf, rel_v, OH);
  gemm_xw<1><<<dim3(64, 8), 256, 0, stream>>>(OH, Wot, bo, d_out);
}